// Round 5
// baseline (415.444 us; speedup 1.0000x reference)
//
#include <hip/hip_runtime.h>

// e3nn fully-connected tensor product, v8: occupancy push to 3 blocks/CU.
// - 16 KB weight stages (8 u), 2-buffer ring -> 32 KB LDS/block (3 blocks fit).
// - One accumulator section at a time: out1's j-components and out2's
//   k-components are OUTER loops that re-stream the (L2-resident) weight
//   slices, so peak live regs ~= f1g(64)+f2g(32)+acc(16..32)+temps < 170.
// - out0 uses 2 accs (vh-split) for MFMA chain ILP; summed at store.
// - v7's proven per-slot sync skeleton: WAITN(N); BAR; [stores]; compute;
//   BAR; issue(t+2). N counted: 4 steady, 20 after a 16-dword store burst,
//   0 at the tail. DMA for slot t+2 overwrites the buffer slot t just read
//   (parity (t+2)&1 == t&1), WAR-safe after the second barrier.

typedef _Float16 f16;
typedef f16 f16x8 __attribute__((ext_vector_type(8)));
typedef float f32x16 __attribute__((ext_vector_type(16)));

#define MFMA32(a, b, c) __builtin_amdgcn_mfma_f32_32x32x16_f16(a, b, c, 0, 0, 0)

// A000 = A011 = A101 = A111 = 1/sqrt(2048); A110 = 1/sqrt(6144)
#define SC_COMMON 0.022097086912079608f
#define SC_110    0.012757759118834242f

// ---------------- weight prep ------------------------------------------------
// ws order: c0=w000, c1=w110, c2=w011, c3=w101, c4=w111 (scales folded).
// B-frag (32x32x16): lane holds B[k=(lane>>5)*8+j][n=lane&31], K-chunk vh.
// idx = ((c*32 + u)*2 + vh)*512 + lane*8 + j
//   element = sc * W[u][ v = vh*16 + (lane>>5)*8 + j ][ w = lane&31 ]
// 16 KB slices: slice id = c*4 + (u>>3), offset slice*8192 f16.
__global__ void prep_w(const float* __restrict__ w000, const float* __restrict__ w011,
                       const float* __restrict__ w101, const float* __restrict__ w110,
                       const float* __restrict__ w111, f16* __restrict__ wsW)
{
    int flat = blockIdx.x * 256 + threadIdx.x;
    if (flat >= 5 * 32768) return;
    int c    = flat >> 15;
    int r    = flat & 32767;
    int j    = r & 7;
    int lane = (r >> 3) & 63;
    int vh   = (r >> 9) & 1;
    int u    = r >> 10;
    int v = vh * 16 + ((lane >> 5) << 3) + j;
    int w = lane & 31;
    const float* src; float sc;
    switch (c) {
        case 0: src = w000; sc = SC_COMMON; break;
        case 1: src = w110; sc = SC_110;    break;
        case 2: src = w011; sc = SC_COMMON; break;
        case 3: src = w101; sc = SC_COMMON; break;
        default: src = w111; sc = SC_COMMON; break;
    }
    wsW[flat] = (f16)(sc * src[u * 1024 + v * 32 + w]);
}

// ---------------- slot compute ----------------------------------------------
// One slot = 8 u (quarter Q of a tensor) x 2 vh. 16 MFMA per slot.
// MODE: 0 = w000 (acc[vh], vh-split), 1 = w110 (acc[vh], A pre-summed over i),
//       2 = w011 component J, 3 = w101 component J, 4 = w111 component J.
template <int Q, int MODE, int J, int NA>
__device__ __forceinline__ void do_slot(f32x16 (&acc)[NA],
                                        const f16* __restrict__ lds,
                                        const f16x8 (&f1g)[4][4],
                                        const f16x8 (&f2g)[4][2], int lane)
{
#pragma unroll
    for (int ul = 0; ul < 8; ++ul) {
#pragma unroll
        for (int vh = 0; vh < 2; ++vh) {
            f16x8 b = *(const f16x8*)(lds + ul * 1024 + vh * 512 + lane * 8);
            if constexpr (MODE == 0) {
                f16x8 a = f1g[0][Q][ul] * f2g[0][vh];
                acc[vh] = MFMA32(a, b, acc[vh]);
            } else if constexpr (MODE == 1) {
                f16x8 a = f1g[1][Q][ul] * f2g[1][vh];
                a += f1g[2][Q][ul] * f2g[2][vh];
                a += f1g[3][Q][ul] * f2g[3][vh];
                acc[vh] = MFMA32(a, b, acc[vh]);
            } else if constexpr (MODE == 2) {
                f16x8 a = f1g[0][Q][ul] * f2g[1 + J][vh];
                acc[0] = MFMA32(a, b, acc[0]);
            } else if constexpr (MODE == 3) {
                f16x8 a = f1g[1 + J][Q][ul] * f2g[0][vh];
                acc[0] = MFMA32(a, b, acc[0]);
            } else {
                // cross component J: (i,j) pairs (1,2),(2,0),(0,1) -> arrs+1
                constexpr int P  = (J == 0) ? 2 : (J == 1) ? 3 : 1;
                constexpr int Q2 = (J == 0) ? 3 : (J == 1) ? 1 : 2;
                f16x8 a = f1g[P][Q][ul] * f2g[Q2][vh]
                        - f1g[Q2][Q][ul] * f2g[P][vh];
                acc[0] = MFMA32(a, b, acc[0]);
            }
        }
    }
}

#define WAITN(N) asm volatile("s_waitcnt vmcnt(" #N ")" ::: "memory")
#define BAR()    __builtin_amdgcn_s_barrier()
#define PRIO1()  __builtin_amdgcn_s_setprio(1)
#define PRIO0()  __builtin_amdgcn_s_setprio(0)

__global__ __launch_bounds__(256, 3)
void tp_main(const float* __restrict__ x1, const float* __restrict__ x2,
             const f16* __restrict__ wsW, float* __restrict__ out)
{
    __shared__ __align__(16) f16 ldsW[2][8192];  // 32 KB: 2-buffer, 16 KB slices

    const int tid = threadIdx.x, lane = tid & 63, wv = tid >> 6;
    const int rowBase = blockIdx.x * 128 + wv * 32;
    const int mrow = lane & 31;          // this lane's row (A and C/D)
    const int half = lane >> 5;          // k-group
    const int klo = half * 8;
    const float4* x1r4 = (const float4*)(x1 + (size_t)(rowBase + mrow) * 128);
    const float4* x2r4 = (const float4*)(x2 + (size_t)(rowBase + mrow) * 128);

    // stage one 16 KB slice into buffer buf (4 x 4 KB per block)
    auto issue = [&](int slice, int buf) {
        const f16* src = wsW + (size_t)slice * 8192;
        f16* dst = &ldsW[buf][0];
#pragma unroll
        for (int it = 0; it < 4; ++it) {
            int o = (it * 256 + tid) * 8;
            __builtin_amdgcn_global_load_lds(
                (const __attribute__((address_space(1))) void*)(src + o),
                (__attribute__((address_space(3))) void*)(dst + o), 16, 0, 0);
        }
    };

    issue(0, 0);  // slice 0 in flight during the whole prologue

    // ---- f1: all 128 features of my row, f16, [arr][quarter][ul] ----
    f16x8 f1g[4][4];
    {
        float b0[32];
#pragma unroll
        for (int g = 0; g < 8; ++g) ((float4*)b0)[g] = x1r4[g];
#pragma unroll
        for (int g = 0; g < 4; ++g)
#pragma unroll
            for (int j = 0; j < 8; ++j) f1g[0][g][j] = (f16)b0[g * 8 + j];
        float b1[96];
#pragma unroll
        for (int g = 0; g < 24; ++g) ((float4*)b1)[g] = x1r4[8 + g];
#pragma unroll
        for (int i = 0; i < 3; ++i)
#pragma unroll
            for (int g = 0; g < 4; ++g)
#pragma unroll
                for (int j = 0; j < 8; ++j)
                    f1g[1 + i][g][j] = (f16)b1[3 * (g * 8 + j) + i];
    }

    // ---- f2: my row's k-slice: v = vh*16 + klo + j, [arr][vh] ----
    f16x8 f2g[4][2];
    {
        float c0[16];
#pragma unroll
        for (int g = 0; g < 2; ++g) ((float4*)c0)[g]     = x2r4[klo / 4 + g];
#pragma unroll
        for (int g = 0; g < 2; ++g) ((float4*)c0)[2 + g] = x2r4[4 + klo / 4 + g];
#pragma unroll
        for (int vh = 0; vh < 2; ++vh)
#pragma unroll
            for (int j = 0; j < 8; ++j) f2g[0][vh][j] = (f16)c0[vh * 8 + j];
        // vec spans: floats [32+3*klo, +24) and [80+3*klo, +24), both 16B-aligned
        float c1[48];
        const int base1 = (32 + 3 * klo) / 4;
#pragma unroll
        for (int g = 0; g < 6; ++g) ((float4*)c1)[g]     = x2r4[base1 + g];
#pragma unroll
        for (int g = 0; g < 6; ++g) ((float4*)c1)[6 + g] = x2r4[base1 + 12 + g];
#pragma unroll
        for (int i = 0; i < 3; ++i)
#pragma unroll
            for (int vh = 0; vh < 2; ++vh)
#pragma unroll
                for (int j = 0; j < 8; ++j)
                    f2g[1 + i][vh][j] = (f16)c1[vh * 24 + 3 * j + i];
    }

    issue(1, 1);  // second prefetch right before the pipeline starts

    // ================= out0: c0 (mode 0) + c1 (mode 1), vh-split accs ======
    {
        f32x16 acc[2] = {};
        WAITN(4);  BAR(); PRIO1(); do_slot<0, 0, 0>(acc, ldsW[0], f1g, f2g, lane); PRIO0(); BAR(); issue(2, 0);
        WAITN(4);  BAR(); PRIO1(); do_slot<1, 0, 0>(acc, ldsW[1], f1g, f2g, lane); PRIO0(); BAR(); issue(3, 1);
        WAITN(4);  BAR(); PRIO1(); do_slot<2, 0, 0>(acc, ldsW[0], f1g, f2g, lane); PRIO0(); BAR(); issue(4, 0);
        WAITN(4);  BAR(); PRIO1(); do_slot<3, 0, 0>(acc, ldsW[1], f1g, f2g, lane); PRIO0(); BAR(); issue(5, 1);
        WAITN(4);  BAR(); PRIO1(); do_slot<0, 1, 0>(acc, ldsW[0], f1g, f2g, lane); PRIO0(); BAR(); issue(6, 0);
        WAITN(4);  BAR(); PRIO1(); do_slot<1, 1, 0>(acc, ldsW[1], f1g, f2g, lane); PRIO0(); BAR(); issue(7, 1);
        WAITN(4);  BAR(); PRIO1(); do_slot<2, 1, 0>(acc, ldsW[0], f1g, f2g, lane); PRIO0(); BAR(); issue(8, 0);
        WAITN(4);  BAR(); PRIO1(); do_slot<3, 1, 0>(acc, ldsW[1], f1g, f2g, lane); PRIO0(); BAR(); issue(9, 1);
        // slot 8 head: store out0 (16 dwords), then compute continues below
        WAITN(4);  BAR();
#pragma unroll
        for (int reg = 0; reg < 16; ++reg) {
            int r = (reg & 3) + 8 * (reg >> 2) + 4 * half;
            out[(size_t)(rowBase + r) * 224 + mrow] = acc[0][reg] + acc[1][reg];
        }
    }

    // ================= out1: per-component j over c2 (mode 2) + c3 (mode 3) =
    // (the WAITN/BAR for the FIRST slot of j=0 was already done above)
    {
        f32x16 acc[1] = {};
        // ---- j = 0 : slots 8..15 ----
        PRIO1(); do_slot<0, 2, 0>(acc, ldsW[0], f1g, f2g, lane); PRIO0(); BAR(); issue(10, 0);
        WAITN(20); BAR(); PRIO1(); do_slot<1, 2, 0>(acc, ldsW[1], f1g, f2g, lane); PRIO0(); BAR(); issue(11, 1);
        WAITN(4);  BAR(); PRIO1(); do_slot<2, 2, 0>(acc, ldsW[0], f1g, f2g, lane); PRIO0(); BAR(); issue(12, 0);
        WAITN(4);  BAR(); PRIO1(); do_slot<3, 2, 0>(acc, ldsW[1], f1g, f2g, lane); PRIO0(); BAR(); issue(13, 1);
        WAITN(4);  BAR(); PRIO1(); do_slot<0, 3, 0>(acc, ldsW[0], f1g, f2g, lane); PRIO0(); BAR(); issue(14, 0);
        WAITN(4);  BAR(); PRIO1(); do_slot<1, 3, 0>(acc, ldsW[1], f1g, f2g, lane); PRIO0(); BAR(); issue(15, 1);
        WAITN(4);  BAR(); PRIO1(); do_slot<2, 3, 0>(acc, ldsW[0], f1g, f2g, lane); PRIO0(); BAR(); issue(8, 0);
        WAITN(4);  BAR(); PRIO1(); do_slot<3, 3, 0>(acc, ldsW[1], f1g, f2g, lane); PRIO0(); BAR(); issue(9, 1);
        // slot 16 head: store j=0, reset acc
        WAITN(4);  BAR();
#pragma unroll
        for (int reg = 0; reg < 16; ++reg) {
            int r = (reg & 3) + 8 * (reg >> 2) + 4 * half;
            out[(size_t)(rowBase + r) * 224 + 32 + 3 * mrow + 0] = acc[0][reg];
        }
        acc[0] = (f32x16)0.0f;
        // ---- j = 1 : slots 16..23 ----
        PRIO1(); do_slot<0, 2, 1>(acc, ldsW[0], f1g, f2g, lane); PRIO0(); BAR(); issue(10, 0);
        WAITN(20); BAR(); PRIO1(); do_slot<1, 2, 1>(acc, ldsW[1], f1g, f2g, lane); PRIO0(); BAR(); issue(11, 1);
        WAITN(4);  BAR(); PRIO1(); do_slot<2, 2, 1>(acc, ldsW[0], f1g, f2g, lane); PRIO0(); BAR(); issue(12, 0);
        WAITN(4);  BAR(); PRIO1(); do_slot<3, 2, 1>(acc, ldsW[1], f1g, f2g, lane); PRIO0(); BAR(); issue(13, 1);
        WAITN(4);  BAR(); PRIO1(); do_slot<0, 3, 1>(acc, ldsW[0], f1g, f2g, lane); PRIO0(); BAR(); issue(14, 0);
        WAITN(4);  BAR(); PRIO1(); do_slot<1, 3, 1>(acc, ldsW[1], f1g, f2g, lane); PRIO0(); BAR(); issue(15, 1);
        WAITN(4);  BAR(); PRIO1(); do_slot<2, 3, 1>(acc, ldsW[0], f1g, f2g, lane); PRIO0(); BAR(); issue(8, 0);
        WAITN(4);  BAR(); PRIO1(); do_slot<3, 3, 1>(acc, ldsW[1], f1g, f2g, lane); PRIO0(); BAR(); issue(9, 1);
        // slot 24 head: store j=1, reset acc
        WAITN(4);  BAR();
#pragma unroll
        for (int reg = 0; reg < 16; ++reg) {
            int r = (reg & 3) + 8 * (reg >> 2) + 4 * half;
            out[(size_t)(rowBase + r) * 224 + 32 + 3 * mrow + 1] = acc[0][reg];
        }
        acc[0] = (f32x16)0.0f;
        // ---- j = 2 : slots 24..31 ----
        PRIO1(); do_slot<0, 2, 2>(acc, ldsW[0], f1g, f2g, lane); PRIO0(); BAR(); issue(10, 0);
        WAITN(20); BAR(); PRIO1(); do_slot<1, 2, 2>(acc, ldsW[1], f1g, f2g, lane); PRIO0(); BAR(); issue(11, 1);
        WAITN(4);  BAR(); PRIO1(); do_slot<2, 2, 2>(acc, ldsW[0], f1g, f2g, lane); PRIO0(); BAR(); issue(12, 0);
        WAITN(4);  BAR(); PRIO1(); do_slot<3, 2, 2>(acc, ldsW[1], f1g, f2g, lane); PRIO0(); BAR(); issue(13, 1);
        WAITN(4);  BAR(); PRIO1(); do_slot<0, 3, 2>(acc, ldsW[0], f1g, f2g, lane); PRIO0(); BAR(); issue(14, 0);
        WAITN(4);  BAR(); PRIO1(); do_slot<1, 3, 2>(acc, ldsW[1], f1g, f2g, lane); PRIO0(); BAR(); issue(15, 1);
        WAITN(4);  BAR(); PRIO1(); do_slot<2, 3, 2>(acc, ldsW[0], f1g, f2g, lane); PRIO0(); BAR(); issue(16, 0);
        WAITN(4);  BAR(); PRIO1(); do_slot<3, 3, 2>(acc, ldsW[1], f1g, f2g, lane); PRIO0(); BAR(); issue(17, 1);
        // slot 32 head: store j=2
        WAITN(4);  BAR();
#pragma unroll
        for (int reg = 0; reg < 16; ++reg) {
            int r = (reg & 3) + 8 * (reg >> 2) + 4 * half;
            out[(size_t)(rowBase + r) * 224 + 32 + 3 * mrow + 2] = acc[0][reg];
        }
    }

    // ================= out2: per-component k over c4 (mode 4) ===============
    {
        f32x16 acc[1] = {};
        // ---- k = 0 : slots 32..35 ----
        PRIO1(); do_slot<0, 4, 0>(acc, ldsW[0], f1g, f2g, lane); PRIO0(); BAR(); issue(18, 0);
        WAITN(20); BAR(); PRIO1(); do_slot<1, 4, 0>(acc, ldsW[1], f1g, f2g, lane); PRIO0(); BAR(); issue(19, 1);
        WAITN(4);  BAR(); PRIO1(); do_slot<2, 4, 0>(acc, ldsW[0], f1g, f2g, lane); PRIO0(); BAR(); issue(16, 0);
        WAITN(4);  BAR(); PRIO1(); do_slot<3, 4, 0>(acc, ldsW[1], f1g, f2g, lane); PRIO0(); BAR(); issue(17, 1);
        // slot 36 head: store k=0, reset acc
        WAITN(4);  BAR();
#pragma unroll
        for (int reg = 0; reg < 16; ++reg) {
            int r = (reg & 3) + 8 * (reg >> 2) + 4 * half;
            out[(size_t)(rowBase + r) * 224 + 128 + 3 * mrow + 0] = acc[0][reg];
        }
        acc[0] = (f32x16)0.0f;
        // ---- k = 1 : slots 36..39 ----
        PRIO1(); do_slot<0, 4, 1>(acc, ldsW[0], f1g, f2g, lane); PRIO0(); BAR(); issue(18, 0);
        WAITN(20); BAR(); PRIO1(); do_slot<1, 4, 1>(acc, ldsW[1], f1g, f2g, lane); PRIO0(); BAR(); issue(19, 1);
        WAITN(4);  BAR(); PRIO1(); do_slot<2, 4, 1>(acc, ldsW[0], f1g, f2g, lane); PRIO0(); BAR(); issue(16, 0);
        WAITN(4);  BAR(); PRIO1(); do_slot<3, 4, 1>(acc, ldsW[1], f1g, f2g, lane); PRIO0(); BAR(); issue(17, 1);
        // slot 40 head: store k=1, reset acc
        WAITN(4);  BAR();
#pragma unroll
        for (int reg = 0; reg < 16; ++reg) {
            int r = (reg & 3) + 8 * (reg >> 2) + 4 * half;
            out[(size_t)(rowBase + r) * 224 + 128 + 3 * mrow + 1] = acc[0][reg];
        }
        acc[0] = (f32x16)0.0f;
        // ---- k = 2 : slots 40..43 (no further prefetch) ----
        PRIO1(); do_slot<0, 4, 2>(acc, ldsW[0], f1g, f2g, lane); PRIO0(); BAR(); issue(18, 0);
        WAITN(20); BAR(); PRIO1(); do_slot<1, 4, 2>(acc, ldsW[1], f1g, f2g, lane); PRIO0(); BAR(); issue(19, 1);
        WAITN(4);  BAR(); PRIO1(); do_slot<2, 4, 2>(acc, ldsW[0], f1g, f2g, lane); PRIO0(); BAR();
        WAITN(0);  BAR(); PRIO1(); do_slot<3, 4, 2>(acc, ldsW[1], f1g, f2g, lane); PRIO0();
        // final store k=2
#pragma unroll
        for (int reg = 0; reg < 16; ++reg) {
            int r = (reg & 3) + 8 * (reg >> 2) + 4 * half;
            out[(size_t)(rowBase + r) * 224 + 128 + 3 * mrow + 2] = acc[0][reg];
        }
    }
}

// ---------------- launch -----------------------------------------------------
extern "C" void kernel_launch(void* const* d_in, const int* in_sizes, int n_in,
                              void* d_out, int out_size, void* d_ws, size_t ws_size,
                              hipStream_t stream)
{
    const float* x1   = (const float*)d_in[0];
    const float* x2   = (const float*)d_in[1];
    const float* w000 = (const float*)d_in[2];
    const float* w011 = (const float*)d_in[3];
    const float* w101 = (const float*)d_in[4];
    const float* w110 = (const float*)d_in[5];
    const float* w111 = (const float*)d_in[6];
    float* out = (float*)d_out;
    f16* wsW = (f16*)d_ws;  // 5 * 32768 f16 = 320 KB

    hipLaunchKernelGGL(prep_w, dim3(640), dim3(256), 0, stream,
                       w000, w011, w101, w110, w111, wsW);

    int n = in_sizes[0] / 128;  // 131072 rows
    hipLaunchKernelGGL(tp_main, dim3(n / 128), dim3(256), 0, stream,
                       x1, x2, wsW, out);
}

// Round 6
// 296.426 us; speedup vs baseline: 1.4015x; 1.4015x over previous
//
#include <hip/hip_runtime.h>

// e3nn fully-connected tensor product, v9: BARRIER-FREE wave-private pipeline.
// One wave owns 32 rows (lane&31 = its row); x1/x2 features in registers.
// Each wave has a PRIVATE 2 x 8 KB LDS ring (4 waves x 16 KB = 64 KB/block,
// 2 blocks/CU) and DMAs its own copy of the weights in 8 KB stages (4 u's,
// 8 global_load_lds each). All hazards are wave-local:
//   top of stage t:  s_waitcnt vmcnt(8)   <- own queue, in-order: waits stage
//                                            t's 8 loads, leaves t+1's 8
//   compute stage t  (ds_read_b128 + MFMA; compiler inserts lgkm waits)
//   s_waitcnt lgkmcnt(0)                  <- buffer t&1 fully consumed
//   issue(t+2) into buffer t&1            <- WAR-safe overwrite
// After a 16-dword store burst the next wait is vmcnt(24) (16 stores + 8
// loads are newer than the target loads; vm ops retire in order).
// ZERO s_barrier: waves free-run, the 2 waves/SIMD slip into antiphase so
// MFMA of one covers VALU/ds_read of the other. Weight DMA is 4x (per-wave
// copies) but wsW (320 KB) is L2-resident -> no extra HBM traffic.

typedef _Float16 f16;
typedef f16 f16x8 __attribute__((ext_vector_type(8)));
typedef float f32x16 __attribute__((ext_vector_type(16)));

#define MFMA32(a, b, c) __builtin_amdgcn_mfma_f32_32x32x16_f16(a, b, c, 0, 0, 0)

// A000 = A011 = A101 = A111 = 1/sqrt(2048); A110 = 1/sqrt(6144)
#define SC_COMMON 0.022097086912079608f
#define SC_110    0.012757759118834242f

// ---------------- weight prep ------------------------------------------------
// ws order: c0=w000, c1=w110, c2=w011, c3=w101, c4=w111 (scales folded).
// B-frag (32x32x16): lane holds B[k=(lane>>5)*8+j][n=lane&31], K-chunk vh.
// idx = ((c*32 + u)*2 + vh)*512 + lane*8 + j
//   element = sc * W[u][ v = vh*16 + (lane>>5)*8 + j ][ w = lane&31 ]
// 8 KB stages: stage t = c*8 + u/4, offset t*4096 f16.
__global__ void prep_w(const float* __restrict__ w000, const float* __restrict__ w011,
                       const float* __restrict__ w101, const float* __restrict__ w110,
                       const float* __restrict__ w111, f16* __restrict__ wsW)
{
    int flat = blockIdx.x * 256 + threadIdx.x;
    if (flat >= 5 * 32768) return;
    int c    = flat >> 15;
    int r    = flat & 32767;
    int j    = r & 7;
    int lane = (r >> 3) & 63;
    int vh   = (r >> 9) & 1;
    int u    = r >> 10;
    int v = vh * 16 + ((lane >> 5) << 3) + j;
    int w = lane & 31;
    const float* src; float sc;
    switch (c) {
        case 0: src = w000; sc = SC_COMMON; break;
        case 1: src = w110; sc = SC_110;    break;
        case 2: src = w011; sc = SC_COMMON; break;
        case 3: src = w101; sc = SC_COMMON; break;
        default: src = w111; sc = SC_COMMON; break;
    }
    wsW[flat] = (f16)(sc * src[u * 1024 + v * 32 + w]);
}

// ---------------- stage compute (4 u-values x 2 vh = 8 B-frags) --------------
// MODE: 0 = w000 (acc[vh] split), 1 = w110 (acc[vh] split, A pre-summed),
//       2 = w011 (3 accs), 3 = w101 (3 accs), 4 = w111 cross (3 accs)
template <int U0, int MODE, int NA>
__device__ __forceinline__ void do4(f32x16 (&acc)[NA],
                                    const f16* __restrict__ lds,
                                    const f16x8 (&f1g)[4][4],
                                    const f16x8 (&f2g)[4][2], int lane)
{
#pragma unroll
    for (int ul = 0; ul < 4; ++ul) {
        const int u = U0 + ul;
#pragma unroll
        for (int vh = 0; vh < 2; ++vh) {
            f16x8 b = *(const f16x8*)(lds + ul * 1024 + vh * 512 + lane * 8);
            if constexpr (MODE == 0) {
                f16x8 a = f1g[0][u >> 3][u & 7] * f2g[0][vh];
                acc[vh] = MFMA32(a, b, acc[vh]);
            } else if constexpr (MODE == 1) {
                f16x8 a = f1g[1][u >> 3][u & 7] * f2g[1][vh];
                a += f1g[2][u >> 3][u & 7] * f2g[2][vh];
                a += f1g[3][u >> 3][u & 7] * f2g[3][vh];
                acc[vh] = MFMA32(a, b, acc[vh]);
            } else if constexpr (MODE == 2) {
#pragma unroll
                for (int j = 0; j < 3; ++j) {
                    f16x8 a = f1g[0][u >> 3][u & 7] * f2g[1 + j][vh];
                    acc[j] = MFMA32(a, b, acc[j]);
                }
            } else if constexpr (MODE == 3) {
#pragma unroll
                for (int j = 0; j < 3; ++j) {
                    f16x8 a = f1g[1 + j][u >> 3][u & 7] * f2g[0][vh];
                    acc[j] = MFMA32(a, b, acc[j]);
                }
            } else {
                // cross: k0:(i=1,j=2)->arrs(2,3); k1:(2,0)->(3,1); k2:(0,1)->(1,2)
#pragma unroll
                for (int k = 0; k < 3; ++k) {
                    constexpr int PP[3] = {2, 3, 1};
                    constexpr int QQ[3] = {3, 1, 2};
                    f16x8 a = f1g[PP[k]][u >> 3][u & 7] * f2g[QQ[k]][vh]
                            - f1g[QQ[k]][u >> 3][u & 7] * f2g[PP[k]][vh];
                    acc[k] = MFMA32(a, b, acc[k]);
                }
            }
        }
    }
}

#define WAITN_IMPL(N) asm volatile("s_waitcnt vmcnt(" #N ")" ::: "memory")
#define WAITN(N) WAITN_IMPL(N)
#define LGKM0()  asm volatile("s_waitcnt lgkmcnt(0)" ::: "memory")

__global__ __launch_bounds__(256, 2)
void tp_main(const float* __restrict__ x1, const float* __restrict__ x2,
             const f16* __restrict__ wsW, float* __restrict__ out)
{
    __shared__ __align__(16) f16 ldsW[4][2][4096];  // per-wave 2 x 8 KB rings

    const int tid = threadIdx.x, lane = tid & 63, wv = tid >> 6;
    const int rowBase = blockIdx.x * 128 + wv * 32;
    const int mrow = lane & 31;          // this lane's row (A and C/D)
    const int half = lane >> 5;          // k-group
    const int klo = half * 8;
    const float4* x1r4 = (const float4*)(x1 + (size_t)(rowBase + mrow) * 128);
    const float4* x2r4 = (const float4*)(x2 + (size_t)(rowBase + mrow) * 128);
    f16* wlds = &ldsW[wv][0][0];

    // stage t in [0,40): 8 KB slice t of wsW -> own buffer buf (8 x 1 KB DMA)
    auto issue = [&](int t, int buf) {
        const f16* src = wsW + (size_t)t * 4096;
        f16* dst = wlds + buf * 4096;
#pragma unroll
        for (int it = 0; it < 8; ++it) {
            int o = (it * 64 + lane) * 8;
            __builtin_amdgcn_global_load_lds(
                (const __attribute__((address_space(1))) void*)(src + o),
                (__attribute__((address_space(3))) void*)(dst + o), 16, 0, 0);
        }
    };

    issue(0, 0);  // stage 0 DMA in flight during the whole prologue

    // ---- f1: all 128 features of my row, f16, [arr][quarter][idx] ----
    f16x8 f1g[4][4];
    {
        float b0[32];
#pragma unroll
        for (int g = 0; g < 8; ++g) ((float4*)b0)[g] = x1r4[g];
#pragma unroll
        for (int g = 0; g < 4; ++g)
#pragma unroll
            for (int j = 0; j < 8; ++j) f1g[0][g][j] = (f16)b0[g * 8 + j];
        float b1[96];
#pragma unroll
        for (int g = 0; g < 24; ++g) ((float4*)b1)[g] = x1r4[8 + g];
#pragma unroll
        for (int i = 0; i < 3; ++i)
#pragma unroll
            for (int g = 0; g < 4; ++g)
#pragma unroll
                for (int j = 0; j < 8; ++j)
                    f1g[1 + i][g][j] = (f16)b1[3 * (g * 8 + j) + i];
    }
    // (consuming the x1 loads retires issue(0)'s DMA from the vm queue view)

    // ---- f2: my row's k-slice: v = vh*16 + klo + j, [arr][vh] ----
    f16x8 f2g[4][2];
    {
        float c0[16];
#pragma unroll
        for (int g = 0; g < 2; ++g) ((float4*)c0)[g]     = x2r4[klo / 4 + g];
#pragma unroll
        for (int g = 0; g < 2; ++g) ((float4*)c0)[2 + g] = x2r4[4 + klo / 4 + g];
#pragma unroll
        for (int vh = 0; vh < 2; ++vh)
#pragma unroll
            for (int j = 0; j < 8; ++j) f2g[0][vh][j] = (f16)c0[vh * 8 + j];
        // vec spans: floats [32+3*klo, +24) and [80+3*klo, +24), both 16B-aligned
        float c1[48];
        const int base1 = (32 + 3 * klo) / 4;
#pragma unroll
        for (int g = 0; g < 6; ++g) ((float4*)c1)[g]     = x2r4[base1 + g];
#pragma unroll
        for (int g = 0; g < 6; ++g) ((float4*)c1)[6 + g] = x2r4[base1 + 12 + g];
#pragma unroll
        for (int i = 0; i < 3; ++i)
#pragma unroll
            for (int vh = 0; vh < 2; ++vh)
#pragma unroll
                for (int j = 0; j < 8; ++j)
                    f2g[1 + i][vh][j] = (f16)c1[vh * 24 + 3 * j + i];
    }

    issue(1, 1);  // one-ahead established

    // STAGE(t): wait own stage-t loads (8 newest = t+1's stay in flight),
    // compute from buffer t&1, drain own ds_reads, refill buffer with t+2.
#define STAGE(T, WN, U0, MODE, ACC) \
    WAITN(WN); \
    do4<U0, MODE>(ACC, wlds + ((T) & 1) * 4096, f1g, f2g, lane); \
    LGKM0(); \
    issue((T) + 2, (T) & 1);

    f32x16 acc0[2] = {};
    // ---- t 0..7: c0 (mode 0) ----
    STAGE(0, 8,  0, 0, acc0)  STAGE(1, 8,  4, 0, acc0)
    STAGE(2, 8,  8, 0, acc0)  STAGE(3, 8, 12, 0, acc0)
    STAGE(4, 8, 16, 0, acc0)  STAGE(5, 8, 20, 0, acc0)
    STAGE(6, 8, 24, 0, acc0)  STAGE(7, 8, 28, 0, acc0)
    // ---- t 8..15: c1 (mode 1) ----
    STAGE(8,  8,  0, 1, acc0) STAGE(9,  8,  4, 1, acc0)
    STAGE(10, 8,  8, 1, acc0) STAGE(11, 8, 12, 1, acc0)
    STAGE(12, 8, 16, 1, acc0) STAGE(13, 8, 20, 1, acc0)
    STAGE(14, 8, 24, 1, acc0)
    // t15 special: compute, store out0 (16 dwords), refill
    WAITN(8);
    do4<28, 1>(acc0, wlds + 4096, f1g, f2g, lane);
#pragma unroll
    for (int reg = 0; reg < 16; ++reg) {
        int r = (reg & 3) + 8 * (reg >> 2) + 4 * half;
        out[(size_t)(rowBase + r) * 224 + mrow] = acc0[0][reg] + acc0[1][reg];
    }
    LGKM0();
    issue(17, 1);

    f32x16 acc1[3] = {};
    // ---- t 16..23: c2 (mode 2); t16 waits past the 16 stores + t17 loads ----
    STAGE(16, 24, 0, 2, acc1) STAGE(17, 8,  4, 2, acc1)
    STAGE(18, 8,  8, 2, acc1) STAGE(19, 8, 12, 2, acc1)
    STAGE(20, 8, 16, 2, acc1) STAGE(21, 8, 20, 2, acc1)
    STAGE(22, 8, 24, 2, acc1) STAGE(23, 8, 28, 2, acc1)
    // ---- t 24..31: c3 (mode 3) ----
    STAGE(24, 8,  0, 3, acc1) STAGE(25, 8,  4, 3, acc1)
    STAGE(26, 8,  8, 3, acc1) STAGE(27, 8, 12, 3, acc1)
    STAGE(28, 8, 16, 3, acc1) STAGE(29, 8, 20, 3, acc1)
    STAGE(30, 8, 24, 3, acc1)
    // t31 special: compute, store out1 (48 dwords, >=16 vm ops), refill
    WAITN(8);
    do4<28, 3>(acc1, wlds + 4096, f1g, f2g, lane);
#pragma unroll
    for (int reg = 0; reg < 16; ++reg) {
        int r = (reg & 3) + 8 * (reg >> 2) + 4 * half;
        size_t base = (size_t)(rowBase + r) * 224 + 32 + 3 * mrow;
        out[base + 0] = acc1[0][reg];
        out[base + 1] = acc1[1][reg];
        out[base + 2] = acc1[2][reg];
    }
    LGKM0();
    issue(33, 1);

    f32x16 acc2[3] = {};
    // ---- t 32..39: c4 (mode 4); t32 waits past >=16 stores + t33 loads ----
    STAGE(32, 24, 0, 4, acc2) STAGE(33, 8,  4, 4, acc2)
    STAGE(34, 8,  8, 4, acc2) STAGE(35, 8, 12, 4, acc2)
    STAGE(36, 8, 16, 4, acc2) STAGE(37, 8, 20, 4, acc2)
    // t38: no further prefetch
    WAITN(8);
    do4<24, 4>(acc2, wlds + 0, f1g, f2g, lane);
    // t39: last stage, drain own queue fully
    WAITN(0);
    do4<28, 4>(acc2, wlds + 4096, f1g, f2g, lane);

#pragma unroll
    for (int reg = 0; reg < 16; ++reg) {
        int r = (reg & 3) + 8 * (reg >> 2) + 4 * half;
        size_t base = (size_t)(rowBase + r) * 224 + 128 + 3 * mrow;
        out[base + 0] = acc2[0][reg];
        out[base + 1] = acc2[1][reg];
        out[base + 2] = acc2[2][reg];
    }
#undef STAGE
}

// ---------------- launch -----------------------------------------------------
extern "C" void kernel_launch(void* const* d_in, const int* in_sizes, int n_in,
                              void* d_out, int out_size, void* d_ws, size_t ws_size,
                              hipStream_t stream)
{
    const float* x1   = (const float*)d_in[0];
    const float* x2   = (const float*)d_in[1];
    const float* w000 = (const float*)d_in[2];
    const float* w011 = (const float*)d_in[3];
    const float* w101 = (const float*)d_in[4];
    const float* w110 = (const float*)d_in[5];
    const float* w111 = (const float*)d_in[6];
    float* out = (float*)d_out;
    f16* wsW = (f16*)d_ws;  // 5 * 32768 f16 = 320 KB

    hipLaunchKernelGGL(prep_w, dim3(640), dim3(256), 0, stream,
                       w000, w011, w101, w110, w111, wsW);

    int n = in_sizes[0] / 128;  // 131072 rows
    hipLaunchKernelGGL(tp_main, dim3(n / 128), dim3(256), 0, stream,
                       x1, x2, wsW, out);
}